// Round 3
// baseline (1380.176 us; speedup 1.0000x reference)
//
#include <hip/hip_runtime.h>
#include <hip/hip_bf16.h>

// Problem constants (match reference)
#define DIMN 100
#define NPATH 8192
#define NT 50
#define HW 256
#define RRATE 0.05f

typedef __hip_bfloat16 bf16;
typedef _Float16 h16;
typedef __attribute__((ext_vector_type(8))) _Float16 h16x8;
typedef __attribute__((ext_vector_type(4))) _Float16 h16x4;
typedef __attribute__((ext_vector_type(4))) float f32x4;

// dtype-flag-branched raw-input loader: f32 != 0 -> fp32 array, else bf16 array
__device__ __forceinline__ float ldin(const void* p, long i, int f32) {
    return f32 ? ((const float*)p)[i] : __bfloat162float(((const bf16*)p)[i]);
}

// ---------------- probe input dtype ----------------
__global__ void probe_kernel(const void* tgp, int* flag) {
    if (threadIdx.x == 0 && blockIdx.x == 0) {
        const unsigned short* u = (const unsigned short*)tgp;
        *flag = (u[1] == 0) ? 1 : 0;   // fp32: high half of 0.0f == 0
    }
}

// ---------------- init: S_carry (f32) from S0; Vt[k][d] = V[d][k] (f32) ----------
__global__ void init_kernel(const void* S0, float* S_carry,
                            const void* V, float* Vt, const int* dflag) {
    const int f = *dflag;
    const long i = (long)blockIdx.x * blockDim.x + threadIdx.x;
    if (i < (long)NPATH * DIMN) S_carry[i] = ldin(S0, i, f);
    if (i < DIMN * DIMN) {
        const long d = i / DIMN, k = i % DIMN;
        Vt[k * DIMN + d] = ldin(V, d * DIMN + k, f);
    }
}

// ---------------- pack all MLP weights to fp16 W^T[n][k] layouts ----------------
// Pg0[256][128]  (k<101 from Wg_in[k][n]); Pgh 3x[256][256]; Pgout[128][256] (n<100)
// Pv0[256][128]; Pvh 3x[256][256]. Total 491520 h16.
__global__ void pack_kernel(const void* Wg_in, const void* Wg_h, const void* Wg_out,
                            const void* Wv_in, const void* Wv_h,
                            h16* __restrict__ P, const int* __restrict__ dflag)
{
    const int f = *dflag;
    const long i = (long)blockIdx.x * blockDim.x + threadIdx.x;
    if (i >= 491520) return;
    float v;
    if (i < 32768) {                      // Pg0
        const int n = i >> 7, k = i & 127;
        v = (k < 101) ? ldin(Wg_in, (long)k * 256 + n, f) : 0.f;
    } else if (i < 229376) {              // Pgh
        const long j = i - 32768;
        const int l = (int)(j >> 16), r = (int)(j & 65535), n = r >> 8, k = r & 255;
        v = ldin(Wg_h, ((long)l * 256 + k) * 256 + n, f);
    } else if (i < 262144) {              // Pgout
        const long j = i - 229376;
        const int n = (int)(j >> 8), k = (int)(j & 255);
        v = (n < 100) ? ldin(Wg_out, (long)k * 100 + n, f) : 0.f;
    } else if (i < 294912) {              // Pv0
        const long j = i - 262144;
        const int n = (int)(j >> 7), k = (int)(j & 127);
        v = (k < 101) ? ldin(Wv_in, (long)k * 256 + n, f) : 0.f;
    } else {                              // Pvh
        const long j = i - 294912;
        const int l = (int)(j >> 16), r = (int)(j & 65535), n = r >> 8, k = r & 255;
        v = ldin(Wv_h, ((long)l * 256 + k) * 256 + n, f);
    }
    P[i] = (h16)v;
}

// ---------------- fp32 GEMM (only for D = dW @ V^T) ----------------
template <bool A_RAW>
__global__ __launch_bounds__(256)
void gemm_kernel(const void* A, long aOff, int K,
                 const float* __restrict__ Bw, int N,
                 float* __restrict__ Cout, const int* __restrict__ dflag)
{
    const int f = *dflag;
    __shared__ float As[8][128];
    __shared__ float Bs[8][128];
    const int tid = threadIdx.x;
    const int tx = tid & 15, ty = tid >> 4;
    const long rowBase = (long)blockIdx.x * 128;
    const int colBase = blockIdx.y * 128;

    float acc[8][8];
#pragma unroll
    for (int i = 0; i < 8; i++)
#pragma unroll
        for (int j = 0; j < 8; j++) acc[i][j] = 0.f;

    for (int k0 = 0; k0 < K; k0 += 8) {
        {
            const int l = tid * 4;
            const int row = l >> 3;
            const int col = l & 7;
            const long abase = aOff + (rowBase + row) * (long)K + (k0 + col);
#pragma unroll
            for (int q = 0; q < 4; q++)
                As[col + q][row] = (k0 + col + q < K) ? ldin(A, abase + q, f) : 0.f;
        }
#pragma unroll
        for (int q = 0; q < 4; q++) {
            const int l = tid + 256 * q;
            const int kk = l >> 7, col = l & 127;
            const int gk = k0 + kk, gc = colBase + col;
            Bs[kk][col] = (gk < K && gc < N) ? Bw[(long)gk * N + gc] : 0.f;
        }
        __syncthreads();
#pragma unroll
        for (int kk = 0; kk < 8; kk++) {
            float a[8], b[8];
            const float4 a0 = *(const float4*)&As[kk][ty * 8];
            const float4 a1 = *(const float4*)&As[kk][ty * 8 + 4];
            const float4 b0 = *(const float4*)&Bs[kk][tx * 8];
            const float4 b1 = *(const float4*)&Bs[kk][tx * 8 + 4];
            a[0]=a0.x;a[1]=a0.y;a[2]=a0.z;a[3]=a0.w;a[4]=a1.x;a[5]=a1.y;a[6]=a1.z;a[7]=a1.w;
            b[0]=b0.x;b[1]=b0.y;b[2]=b0.z;b[3]=b0.w;b[4]=b1.x;b[5]=b1.y;b[6]=b1.z;b[7]=b1.w;
#pragma unroll
            for (int i = 0; i < 8; i++)
#pragma unroll
                for (int j = 0; j < 8; j++)
                    acc[i][j] += a[i] * b[j];
        }
        __syncthreads();
    }

#pragma unroll
    for (int i = 0; i < 8; i++) {
        const long row = rowBase + ty * 8 + i;
        const int colb = colBase + tx * 8;
        if (colb + 7 < N) {
            float4* cp = (float4*)(Cout + row * (long)N + colb);
            cp[0] = make_float4(acc[i][0], acc[i][1], acc[i][2], acc[i][3]);
            cp[1] = make_float4(acc[i][4], acc[i][5], acc[i][6], acc[i][7]);
        } else {
#pragma unroll
            for (int j = 0; j < 8; j++)
                if (colb + j < N) Cout[row * (long)N + colb + j] = acc[i][j];
        }
    }
}

// ---------------- chunked S scan: emits fp16 S (padded 104), vol in-place over D --
// Sh row layout (104 h16): [0]=t, [1..100]=S, [101..103]=0  (t embedded so the MLP
// staging is a straight vector copy). vol = s*D*sqrt(h); S_new = s*(1+r*h) + vol.
__global__ __launch_bounds__(256)
void scan_chunk_kernel(float* __restrict__ S_carry, float* __restrict__ D,
                       const void* tgp, h16* __restrict__ Sh,
                       int t0, int Cg, void* outBase, h16* __restrict__ Shf,
                       int writeSf, const int* __restrict__ dflag)
{
    const int f = *dflag;
    const long idx = (long)blockIdx.x * blockDim.x + threadIdx.x;
    if (idx >= (long)NPATH * DIMN) return;
    const long b = idx / DIMN;
    const int d = (int)(idx - b * DIMN);
    float s = S_carry[idx];
    for (int lt = 0; lt < Cg; lt++) {
        const int t = t0 + lt;
        const float h = ldin(tgp, t + 1, f) - ldin(tgp, t, f);
        const long off = (long)lt * (NPATH * DIMN) + idx;
        const float vol = s * D[off] * sqrtf(h);
        const long shr = ((long)lt * NPATH + b) * 104;
        Sh[shr + 1 + d] = (h16)s;
        if (d == 0) Sh[shr] = (h16)ldin(tgp, t, f);
        if (d < 3) Sh[shr + 101 + d] = (h16)0.f;
        D[off] = vol;
        s = s + RRATE * s * h + vol;
    }
    S_carry[idx] = s;
    if (writeSf) {
        if (f) ((float*)outBase)[NPATH + idx] = s;
        else   ((bf16*)outBase)[NPATH + idx] = __float2bfloat16(s);
        Shf[b * 104 + 1 + d] = (h16)s;
        if (d == 0) Shf[b * 104] = (h16)ldin(tgp, NT - 1, f);
        if (d < 3) Shf[b * 104 + 101 + d] = (h16)0.f;
    }
}

// ---------------- fused MFMA fp16 MLP building blocks ----------------
// TRANSPOSED-OUTPUT scheme: mfma(w_frag, h_frag, acc) -> D: col(lane&15)=H-row,
// row(quad*4+reg)=output column. Bias is folded into acc INIT (MFMA C-in).
// layer_mfma<KP,NTW>: compile-time shapes -> full k-unroll, 2-deep weight
// register pipeline (wf[2][NTW], kt+2 prefetch) so the L2 weight-load latency
// hides under ~2 kt of MFMA issue instead of being fully exposed per kt.
template<int NTW>
__device__ __forceinline__ void init_acc(f32x4 acc[4][4], const float* __restrict__ bsrc,
                                         int nb16, int quad)
{
#pragma unroll
    for (int wt = 0; wt < NTW; wt++) {
        const f32x4 b4 = *(const f32x4*)(bsrc + nb16 + wt * 16 + quad * 4);
#pragma unroll
        for (int rt = 0; rt < 4; rt++) acc[wt][rt] = b4;
    }
}

template<int KP, int NTW>
__device__ __forceinline__ void layer_mfma(const h16* __restrict__ P,
                                           const h16 (*__restrict__ Hsp)[264],
                                           int nb16, int m, int quad,
                                           f32x4 acc[4][4])
{
    constexpr int NKT = KP >> 5;
    const h16* pw = P + (long)(nb16 + m) * KP + quad * 8;
    h16x8 wf[2][NTW];
#pragma unroll
    for (int wt = 0; wt < NTW; wt++)
        wf[0][wt] = *(const h16x8*)(pw + wt * 16 * KP);
#pragma unroll
    for (int wt = 0; wt < NTW; wt++)
        wf[1][wt] = *(const h16x8*)(pw + wt * 16 * KP + 32);
#pragma unroll
    for (int kt = 0; kt < NKT; kt++) {
#pragma unroll
        for (int rt = 0; rt < 4; rt++) {
            const h16x8 hf = *(const h16x8*)&Hsp[rt * 16 + m][(kt << 5) + quad * 8];
#pragma unroll
            for (int wt = 0; wt < NTW; wt++)
                acc[wt][rt] = __builtin_amdgcn_mfma_f32_16x16x32_f16(
                    wf[kt & 1][wt], hf, acc[wt][rt], 0, 0, 0);
        }
        if (kt + 2 < NKT) {
#pragma unroll
            for (int wt = 0; wt < NTW; wt++)
                wf[kt & 1][wt] = *(const h16x8*)(pw + wt * 16 * KP + (kt + 2) * 32);
        }
    }
}

__device__ __forceinline__ void writeback4(f32x4 acc[4][4], h16 (*Hsp)[264],
                                           int nb16, int m, int quad)
{
    __syncthreads();   // all waves done READING Hs this layer
#pragma unroll
    for (int wt = 0; wt < 4; wt++) {
        const int cb = nb16 + wt * 16 + quad * 4;
#pragma unroll
        for (int rt = 0; rt < 4; rt++) {
            const h16x4 pk = {(h16)fmaxf(acc[wt][rt][0], 0.f),
                              (h16)fmaxf(acc[wt][rt][1], 0.f),
                              (h16)fmaxf(acc[wt][rt][2], 0.f),
                              (h16)fmaxf(acc[wt][rt][3], 0.f)};
            *(h16x4*)&Hsp[rt * 16 + m][cb] = pk;
        }
    }
    __syncthreads();   // writes visible before next layer reads
}

// ---------------- fused MFMA fp16 MLP: 64 rows/block, 4 waves split N ----------
template <bool GNET>
__global__ __launch_bounds__(256, 4)
void mlp16_kernel(const h16* __restrict__ Sh, const float* __restrict__ vol,
                  const h16* __restrict__ P0, const h16* __restrict__ Ph,
                  const h16* __restrict__ Pout,
                  const void* b_in, const void* b_h, const void* b_out,
                  const void* wv_out, const void* tgp, int t0,
                  float* __restrict__ outv, const int* __restrict__ dflag)
{
    const int f = *dflag;
    __shared__ __align__(16) h16 Hs[64][264];       // 33,792 B
    __shared__ __align__(16) float bias_s[4][256];  // 4,096 B (layer biases, f32)
    __shared__ __align__(16) float ex_s[256];       // GNET: padded b_out; VNET: wv_out
    __shared__ float Ps[64][4];
    const int tid = threadIdx.x;
    const int w = tid >> 6, lane = tid & 63, quad = lane >> 4, m = lane & 15;
    const long row0 = (long)blockIdx.x * 64;
    const int nb16 = w * 64;

    // ---- preload biases (+ extra vector) into LDS ----
    bias_s[0][tid] = ldin(b_in, tid, f);
    bias_s[1][tid] = ldin(b_h, tid, f);
    bias_s[2][tid] = ldin(b_h, 256 + tid, f);
    bias_s[3][tid] = ldin(b_h, 512 + tid, f);
    if (GNET) {
        if (tid < 128) ex_s[tid] = (tid < DIMN) ? ldin(b_out, tid, f) : 0.f;
    } else {
        ex_s[tid] = ldin(wv_out, tid, f);
    }

    // ---- stage layer-0 input: Sh rows are already [t, S, 0,0,0] -> vector copy ----
    {
        const int r = tid >> 2, j = tid & 3;
        const h16* src = Sh + (row0 + r) * 104;
        h16* dst = &Hs[r][0];
#pragma unroll
        for (int q = 0; q < 4; q++) {
            const int c = j + q * 4;
            if (c < 13)
                *(h16x8*)(dst + c * 8) = *(const h16x8*)(src + c * 8);
        }
        if (j >= 1) {                      // zero cols 104..127 (chunks 13,14,15)
            const h16x8 z = {};
            *(h16x8*)(dst + (12 + j) * 8) = z;
        }
    }
    __syncthreads();   // staging + bias visible to all waves

    f32x4 acc[4][4];   // acc[wt][rt]: rows rt*16+m, cols nb16+wt*16+quad*4+reg

    // ---- layer 0 (K=128) ----
    init_acc<4>(acc, &bias_s[0][0], nb16, quad);
    layer_mfma<128, 4>(P0, Hs, nb16, m, quad, acc);
    writeback4(acc, Hs, nb16, m, quad);

    // ---- hidden layers 1..3 (K=256) ----
    for (int li = 1; li < 4; li++) {
        init_acc<4>(acc, &bias_s[li][0], nb16, quad);
        layer_mfma<256, 4>(Ph + (long)(li - 1) * 65536, Hs, nb16, m, quad, acc);
        writeback4(acc, Hs, nb16, m, quad);
    }

    if (GNET) {
        // ---- output layer (N=100 pad 128, NTW=2), bias folded into init ----
        init_acc<2>(acc, ex_s, w * 32, quad);
        layer_mfma<256, 2>(Pout, Hs, w * 32, m, quad, acc);

        // stoch = sum_col grad*vol  (vol already has sqrt(h))
        float p[4] = {0.f, 0.f, 0.f, 0.f};
#pragma unroll
        for (int wt = 0; wt < 2; wt++) {
            const int cb = w * 32 + wt * 16 + quad * 4;
            if (cb < DIMN) {   // cb multiple of 4 -> cb<=96 -> cb+3<=99
#pragma unroll
                for (int rt = 0; rt < 4; rt++) {
                    const long r = row0 + rt * 16 + m;
                    const float4 vv = *(const float4*)&vol[r * DIMN + cb];
                    p[rt] += acc[wt][rt][0] * vv.x + acc[wt][rt][1] * vv.y
                           + acc[wt][rt][2] * vv.z + acc[wt][rt][3] * vv.w;
                }
            }
        }
#pragma unroll
        for (int rt = 0; rt < 4; rt++) {
            float v = p[rt];
            v += __shfl_xor(v, 16);
            v += __shfl_xor(v, 32);
            if (quad == 0) Ps[rt * 16 + m][w] = v;
        }
        __syncthreads();
        if (tid < 64)
            outv[row0 + tid] = Ps[tid][0] + Ps[tid][1] + Ps[tid][2] + Ps[tid][3];
    } else {
        // v = Hs . w_out + b_out (256 -> 1), 4 threads per row
        const int r = tid & 63, part = tid >> 6;
        float s = 0.f;
#pragma unroll
        for (int c = 0; c < 8; c++) {
            const h16x8 hv = *(const h16x8*)&Hs[r][part * 64 + c * 8];
#pragma unroll
            for (int q = 0; q < 8; q++)
                s += (float)hv[q] * ex_s[part * 64 + c * 8 + q];
        }
        Ps[r][part] = s;
        __syncthreads();
        if (tid < 64)
            outv[row0 + tid] = Ps[tid][0] + Ps[tid][1] + Ps[tid][2] + Ps[tid][3]
                               + ldin(b_out, 0, f);
    }
}

// ---------------- final: error accumulation + v_f ----------------
__global__ void final_kernel(const float* __restrict__ v_all, const float* __restrict__ stoch,
                             const void* tgp, void* out, const int* __restrict__ dflag)
{
    const int f = *dflag;
    const int b = blockIdx.x * blockDim.x + threadIdx.x;
    if (b >= NPATH) return;
    float err = 0.f;
    for (int i = 0; i < NT - 1; i++) {
        const float h = ldin(tgp, i + 1, f) - ldin(tgp, i, f);
        const float e = v_all[(i + 1) * NPATH + b] - v_all[i * NPATH + b] * (1.f + RRATE * h)
                        - stoch[i * NPATH + b];
        err += e * e;
    }
    const long eoff = (long)NPATH + (long)NPATH * DIMN;
    const float vf = v_all[(long)(NT - 1) * NPATH + b];
    if (f) {
        ((float*)out)[b] = vf;
        ((float*)out)[eoff + b] = err;
    } else {
        ((bf16*)out)[b] = __float2bfloat16(vf);
        ((bf16*)out)[eoff + b] = __float2bfloat16(err);
    }
}

static inline int imin(int a, int b) { return a < b ? a : b; }

extern "C" void kernel_launch(void* const* d_in, const int* in_sizes, int n_in,
                              void* d_out, int out_size, void* d_ws, size_t ws_size,
                              hipStream_t stream) {
    const void* S0    = d_in[0];
    const void* dW    = d_in[1];
    const void* tg    = d_in[2];
    const void* V     = d_in[3];
    const void* Wg_in = d_in[4];
    const void* bg_in = d_in[5];
    const void* Wg_h  = d_in[6];
    const void* bg_h  = d_in[7];
    const void* Wg_out= d_in[8];
    const void* bg_out= d_in[9];
    const void* Wv_in = d_in[10];
    const void* bv_in = d_in[11];
    const void* Wv_h  = d_in[12];
    const void* bv_h  = d_in[13];
    const void* Wv_out= d_in[14];
    const void* bv_out= d_in[15];

    const size_t SZ_SD  = (size_t)NPATH * DIMN * 4;    // 3.28 MB (f32 per timestep)
    const size_t SZ_SH  = (size_t)NPATH * 104 * 2;     // 1.70 MB (fp16 padded S)

    // ---- carve workspace ----
    char* p = (char*)d_ws;
    auto carve = [&](size_t bytes) -> char* {
        char* r = p;
        p += (bytes + 255) & ~(size_t)255;
        return r;
    };
    int*   dflag     = (int*)carve(256);
    float* S_carry   = (float*)carve(SZ_SD);
    float* Vt        = (float*)carve((size_t)DIMN * DIMN * 4);
    float* v_all     = (float*)carve((size_t)NT * NPATH * 4);
    float* stoch_all = (float*)carve((size_t)(NT - 1) * NPATH * 4);
    h16*   Shf       = (h16*)carve(SZ_SH);
    h16*   Pk        = (h16*)carve((size_t)491520 * 2);     // packed fp16 weights
    const size_t fixed = (size_t)(p - (char*)d_ws);

    // packed-weight sub-pointers
    h16* Pg0   = Pk;
    h16* Pgh   = Pk + 32768;
    h16* Pgout = Pk + 229376;
    h16* Pv0   = Pk + 262144;
    h16* Pvh   = Pk + 294912;

    // adaptive time-chunk: per-timestep = D/vol (f32) + Sh (fp16)
    const size_t perC = SZ_SD + SZ_SH;                       // 4.98 MB
    size_t avail = (ws_size > fixed + 65536) ? (ws_size - fixed - 65536) : 0;
    int C = (int)(avail / perC);
    if (C < 1) C = 1;
    if (C > NT - 1) C = NT - 1;
    float* D_chunk = (float*)carve((size_t)C * SZ_SD);       // vol written in-place
    h16*   Sh      = (h16*)carve((size_t)C * SZ_SH);

    // ---- prep ----
    probe_kernel<<<dim3(1), dim3(64), 0, stream>>>(tg, dflag);
    init_kernel<<<dim3((NPATH * DIMN + 255) / 256), dim3(256), 0, stream>>>(S0, S_carry, V, Vt, dflag);
    pack_kernel<<<dim3(1920), dim3(256), 0, stream>>>(Wg_in, Wg_h, Wg_out, Wv_in, Wv_h, Pk, dflag);

    // ---- chunk loop over timesteps t in [0, 49) ----
    for (int t0 = 0; t0 < NT - 1; t0 += C) {
        const int Cg = imin(C, NT - 1 - t0);
        const int rows = Cg * NPATH;

        // D = dW[t0..t0+Cg) @ V^T
        gemm_kernel<true><<<dim3(rows / 128, 1), 256, 0, stream>>>(
            dW, (long)t0 * NPATH * DIMN, DIMN, Vt, DIMN, D_chunk, dflag);

        // scan: Sh (fp16), vol in-place over D, advance S_carry; S_f + Shf on last chunk
        scan_chunk_kernel<<<dim3((NPATH * DIMN + 255) / 256), 256, 0, stream>>>(
            S_carry, D_chunk, tg, Sh, t0, Cg, d_out, Shf,
            (t0 + Cg == NT - 1) ? 1 : 0, dflag);

        // g-net (MFMA, fused stoch epilogue)
        mlp16_kernel<true><<<dim3(rows / 64), 256, 0, stream>>>(
            Sh, D_chunk, Pg0, Pgh, Pgout, bg_in, bg_h, bg_out,
            nullptr, tg, t0, stoch_all + (long)t0 * NPATH, dflag);

        // v-net (MFMA, fused output dot)
        mlp16_kernel<false><<<dim3(rows / 64), 256, 0, stream>>>(
            Sh, nullptr, Pv0, Pvh, nullptr, bv_in, bv_h, bv_out,
            Wv_out, tg, t0, v_all + (long)t0 * NPATH, dflag);
    }

    // ---- v at t = 49 from Shf ----
    mlp16_kernel<false><<<dim3(NPATH / 64), 256, 0, stream>>>(
        Shf, nullptr, Pv0, Pvh, nullptr, bv_in, bv_h, bv_out,
        Wv_out, tg, NT - 1, v_all + (long)(NT - 1) * NPATH, dflag);

    // ---- error + v_f ----
    final_kernel<<<dim3(NPATH / 256), 256, 0, stream>>>(v_all, stoch_all, tg, d_out, dflag);
}

// Round 5
// 1132.627 us; speedup vs baseline: 1.2186x; 1.2186x over previous
//
#include <hip/hip_runtime.h>
#include <hip/hip_bf16.h>

// Problem constants (match reference)
#define DIMN 100
#define NPATH 8192
#define NT 50
#define HW 256
#define RRATE 0.05f

typedef __hip_bfloat16 bf16;
typedef _Float16 h16;
typedef __attribute__((ext_vector_type(8))) _Float16 h16x8;
typedef __attribute__((ext_vector_type(4))) _Float16 h16x4;
typedef __attribute__((ext_vector_type(4))) float f32x4;

// dtype-flag-branched raw-input loader: f32 != 0 -> fp32 array, else bf16 array
__device__ __forceinline__ float ldin(const void* p, long i, int f32) {
    return f32 ? ((const float*)p)[i] : __bfloat162float(((const bf16*)p)[i]);
}

// ---------------- probe input dtype ----------------
__global__ void probe_kernel(const void* tgp, int* flag) {
    if (threadIdx.x == 0 && blockIdx.x == 0) {
        const unsigned short* u = (const unsigned short*)tgp;
        *flag = (u[1] == 0) ? 1 : 0;   // fp32: high half of 0.0f == 0
    }
}

// ---------------- init: S_carry (f32) from S0; Vt[k][d] = V[d][k] (f32) ----------
__global__ void init_kernel(const void* S0, float* S_carry,
                            const void* V, float* Vt, const int* dflag) {
    const int f = *dflag;
    const long i = (long)blockIdx.x * blockDim.x + threadIdx.x;
    if (i < (long)NPATH * DIMN) S_carry[i] = ldin(S0, i, f);
    if (i < DIMN * DIMN) {
        const long d = i / DIMN, k = i % DIMN;
        Vt[k * DIMN + d] = ldin(V, d * DIMN + k, f);
    }
}

// ---------------- pack all MLP weights, MFMA-TILE-CONTIGUOUS fp16 ----------------
// Each 16(n)x32(k) tile = 512 h16 = 1KB contiguous, laid out in MFMA lane order:
//   tile(tn,tk) element (lane,e) = W^T[tn*16+(lane&15)][tk*32+(lane>>4)*8+e]
// so a wave's fragment load is exactly base + lane*16B (fully coalesced).
// Tile order: row-major (tn, tk). Matrix offsets (h16): Pg0=0 (16x4 tiles),
// Pgh=32768 (3x 16x8), Pgout=229376 (8x8), Pv0=262144 (16x4), Pvh=294912 (3x 16x8).
__global__ void pack_kernel(const void* Wg_in, const void* Wg_h, const void* Wg_out,
                            const void* Wv_in, const void* Wv_h,
                            h16* __restrict__ P, const int* __restrict__ dflag)
{
    const int f = *dflag;
    const long i = (long)blockIdx.x * blockDim.x + threadIdx.x;
    if (i >= 491520) return;
    long j; int NTk, kind; const void* src; long soff = 0;
    if (i < 32768)       { j = i;          NTk = 4; kind = 0; src = Wg_in; }
    else if (i < 229376) { long t = i - 32768;  j = t & 65535; NTk = 8; kind = 1; src = Wg_h;
                           soff = (long)(t >> 16) * 65536; }
    else if (i < 262144) { j = i - 229376; NTk = 8; kind = 2; src = Wg_out; }
    else if (i < 294912) { j = i - 262144; NTk = 4; kind = 0; src = Wv_in; }
    else                 { long t = i - 294912; j = t & 65535; NTk = 8; kind = 1; src = Wv_h;
                           soff = (long)(t >> 16) * 65536; }
    const int tile = (int)(j >> 9), lane = (int)((j >> 3) & 63), e = (int)(j & 7);
    const int tn = tile / NTk, tk = tile - tn * NTk;
    const int n = tn * 16 + (lane & 15);
    const int k = tk * 32 + (lane >> 4) * 8 + e;
    float v;
    if (kind == 0)      v = (k < 101) ? ldin(src, (long)k * 256 + n, f) : 0.f;  // W_in [101][256]
    else if (kind == 1) v = ldin(src, soff + (long)k * 256 + n, f);             // W_h  [256][256]
    else                v = (n < 100) ? ldin(src, (long)k * 100 + n, f) : 0.f;  // W_out[256][100]
    P[i] = (h16)v;
}

// ---------------- fp32 GEMM (only for D = dW @ V^T) ----------------
template <bool A_RAW>
__global__ __launch_bounds__(256)
void gemm_kernel(const void* A, long aOff, int K,
                 const float* __restrict__ Bw, int N,
                 float* __restrict__ Cout, const int* __restrict__ dflag)
{
    const int f = *dflag;
    __shared__ float As[8][128];
    __shared__ float Bs[8][128];
    const int tid = threadIdx.x;
    const int tx = tid & 15, ty = tid >> 4;
    const long rowBase = (long)blockIdx.x * 128;
    const int colBase = blockIdx.y * 128;

    float acc[8][8];
#pragma unroll
    for (int i = 0; i < 8; i++)
#pragma unroll
        for (int j = 0; j < 8; j++) acc[i][j] = 0.f;

    for (int k0 = 0; k0 < K; k0 += 8) {
        {
            const int l = tid * 4;
            const int row = l >> 3;
            const int col = l & 7;
            const long abase = aOff + (rowBase + row) * (long)K + (k0 + col);
#pragma unroll
            for (int q = 0; q < 4; q++)
                As[col + q][row] = (k0 + col + q < K) ? ldin(A, abase + q, f) : 0.f;
        }
#pragma unroll
        for (int q = 0; q < 4; q++) {
            const int l = tid + 256 * q;
            const int kk = l >> 7, col = l & 127;
            const int gk = k0 + kk, gc = colBase + col;
            Bs[kk][col] = (gk < K && gc < N) ? Bw[(long)gk * N + gc] : 0.f;
        }
        __syncthreads();
#pragma unroll
        for (int kk = 0; kk < 8; kk++) {
            float a[8], b[8];
            const float4 a0 = *(const float4*)&As[kk][ty * 8];
            const float4 a1 = *(const float4*)&As[kk][ty * 8 + 4];
            const float4 b0 = *(const float4*)&Bs[kk][tx * 8];
            const float4 b1 = *(const float4*)&Bs[kk][tx * 8 + 4];
            a[0]=a0.x;a[1]=a0.y;a[2]=a0.z;a[3]=a0.w;a[4]=a1.x;a[5]=a1.y;a[6]=a1.z;a[7]=a1.w;
            b[0]=b0.x;b[1]=b0.y;b[2]=b0.z;b[3]=b0.w;b[4]=b1.x;b[5]=b1.y;b[6]=b1.z;b[7]=b1.w;
#pragma unroll
            for (int i = 0; i < 8; i++)
#pragma unroll
                for (int j = 0; j < 8; j++)
                    acc[i][j] += a[i] * b[j];
        }
        __syncthreads();
    }

#pragma unroll
    for (int i = 0; i < 8; i++) {
        const long row = rowBase + ty * 8 + i;
        const int colb = colBase + tx * 8;
        if (colb + 7 < N) {
            float4* cp = (float4*)(Cout + row * (long)N + colb);
            cp[0] = make_float4(acc[i][0], acc[i][1], acc[i][2], acc[i][3]);
            cp[1] = make_float4(acc[i][4], acc[i][5], acc[i][6], acc[i][7]);
        } else {
#pragma unroll
            for (int j = 0; j < 8; j++)
                if (colb + j < N) Cout[row * (long)N + colb + j] = acc[i][j];
        }
    }
}

// ---------------- chunked S scan: emits fp16 S (padded 104), vol in-place over D --
// Sh row layout (104 h16): [0]=t, [1..100]=S, [101..103]=0  (t embedded so the MLP
// staging is a straight vector copy). vol = s*D*sqrt(h); S_new = s*(1+r*h) + vol.
__global__ __launch_bounds__(256)
void scan_chunk_kernel(float* __restrict__ S_carry, float* __restrict__ D,
                       const void* tgp, h16* __restrict__ Sh,
                       int t0, int Cg, void* outBase, h16* __restrict__ Shf,
                       int writeSf, const int* __restrict__ dflag)
{
    const int f = *dflag;
    const long idx = (long)blockIdx.x * blockDim.x + threadIdx.x;
    if (idx >= (long)NPATH * DIMN) return;
    const long b = idx / DIMN;
    const int d = (int)(idx - b * DIMN);
    float s = S_carry[idx];
    for (int lt = 0; lt < Cg; lt++) {
        const int t = t0 + lt;
        const float h = ldin(tgp, t + 1, f) - ldin(tgp, t, f);
        const long off = (long)lt * (NPATH * DIMN) + idx;
        const float vol = s * D[off] * sqrtf(h);
        const long shr = ((long)lt * NPATH + b) * 104;
        Sh[shr + 1 + d] = (h16)s;
        if (d == 0) Sh[shr] = (h16)ldin(tgp, t, f);
        if (d < 3) Sh[shr + 101 + d] = (h16)0.f;
        D[off] = vol;
        s = s + RRATE * s * h + vol;
    }
    S_carry[idx] = s;
    if (writeSf) {
        if (f) ((float*)outBase)[NPATH + idx] = s;
        else   ((bf16*)outBase)[NPATH + idx] = __float2bfloat16(s);
        Shf[b * 104 + 1 + d] = (h16)s;
        if (d == 0) Shf[b * 104] = (h16)ldin(tgp, NT - 1, f);
        if (d < 3) Shf[b * 104 + 101 + d] = (h16)0.f;
    }
}

// ---------------- fused MFMA fp16 MLP building blocks ----------------
// TRANSPOSED-OUTPUT scheme: mfma(w_frag, h_frag, acc) -> D: col(lane&15)=H-row,
// row(quad*4+reg)=output column. Bias folded into acc INIT (MFMA C-in).
// 8 waves/block (512 thr), NTW=2 col-tiles/wave: same LDS per block -> still
// 4 blocks/CU but 32 waves/CU (2x TLP). Weights are tile-contiguous: each wf
// load is base + lane*16B, fully coalesced, constant per-kt offsets.
template<int NTW>
__device__ __forceinline__ void init_acc(f32x4 acc[2][4], const float* __restrict__ bsrc,
                                         int nb16, int quad)
{
#pragma unroll
    for (int wt = 0; wt < NTW; wt++) {
        const f32x4 b4 = *(const f32x4*)(bsrc + nb16 + wt * 16 + quad * 4);
#pragma unroll
        for (int rt = 0; rt < 4; rt++) acc[wt][rt] = b4;
    }
}

template<int KP, int NTW>
__device__ __forceinline__ void layer_mfma(const h16* __restrict__ P,
                                           const h16 (*__restrict__ Hsp)[264],
                                           int tn0, int m, int quad, int lane,
                                           f32x4 acc[2][4])
{
    constexpr int NKT = KP >> 5;            // k-tiles (32 k each)
    constexpr int TSTRIDE = NKT * 512;      // h16 per n-tile row of tiles
    const h16* pw = P + (long)tn0 * TSTRIDE + lane * 8;
    h16x8 wf[2][NTW];
#pragma unroll
    for (int wt = 0; wt < NTW; wt++)
        wf[0][wt] = *(const h16x8*)(pw + wt * TSTRIDE);
#pragma unroll
    for (int wt = 0; wt < NTW; wt++)
        wf[1][wt] = *(const h16x8*)(pw + wt * TSTRIDE + 512);
#pragma unroll
    for (int kt = 0; kt < NKT; kt++) {
#pragma unroll
        for (int rt = 0; rt < 4; rt++) {
            const h16x8 hf = *(const h16x8*)&Hsp[rt * 16 + m][(kt << 5) + quad * 8];
#pragma unroll
            for (int wt = 0; wt < NTW; wt++)
                acc[wt][rt] = __builtin_amdgcn_mfma_f32_16x16x32_f16(
                    wf[kt & 1][wt], hf, acc[wt][rt], 0, 0, 0);
        }
        if (kt + 2 < NKT) {
#pragma unroll
            for (int wt = 0; wt < NTW; wt++)
                wf[kt & 1][wt] = *(const h16x8*)(pw + wt * TSTRIDE + (kt + 2) * 512);
        }
    }
}

template<int NTW>
__device__ __forceinline__ void writeback(f32x4 acc[2][4], h16 (*Hsp)[264],
                                          int nb16, int m, int quad)
{
    __syncthreads();   // all waves done READING Hs this layer
#pragma unroll
    for (int wt = 0; wt < NTW; wt++) {
        const int cb = nb16 + wt * 16 + quad * 4;
#pragma unroll
        for (int rt = 0; rt < 4; rt++) {
            const h16x4 pk = {(h16)fmaxf(acc[wt][rt][0], 0.f),
                              (h16)fmaxf(acc[wt][rt][1], 0.f),
                              (h16)fmaxf(acc[wt][rt][2], 0.f),
                              (h16)fmaxf(acc[wt][rt][3], 0.f)};
            *(h16x4*)&Hsp[rt * 16 + m][cb] = pk;
        }
    }
    __syncthreads();   // writes visible before next layer reads
}

// ---------------- fused MFMA fp16 MLP: 64 rows/block, 8 waves split N ----------
template <bool GNET>
__global__ __launch_bounds__(512, 8)
void mlp16_kernel(const h16* __restrict__ Sh, const float* __restrict__ vol,
                  const h16* __restrict__ P0, const h16* __restrict__ Ph,
                  const h16* __restrict__ Pout,
                  const void* b_in, const void* b_h, const void* b_out,
                  const void* wv_out, const void* tgp, int t0,
                  float* __restrict__ outv, const int* __restrict__ dflag)
{
    const int f = *dflag;
    __shared__ __align__(16) h16 Hs[64][264];       // 33,792 B
    __shared__ __align__(16) float bias_s[4][256];  // 4,096 B
    __shared__ __align__(16) float ex_s[256];       // 1,024 B (GNET: b_out pad; VNET: wv_out)
    __shared__ float Ps[64][8];                     // 2,048 B  (total 40,960 = 4 blocks/CU)
    const int tid = threadIdx.x;
    const int w = tid >> 6, lane = tid & 63, quad = lane >> 4, m = lane & 15;
    const long row0 = (long)blockIdx.x * 64;

    // ---- preload biases (+ extra vector) into LDS (512 threads, 2 each) ----
    {
        const int l = tid >> 7, c = (tid & 127) << 1;
        const void* bp = (l == 0) ? b_in : b_h;
        const long bo = (l == 0) ? 0 : (long)(l - 1) * 256;
        bias_s[l][c]     = ldin(bp, bo + c, f);
        bias_s[l][c + 1] = ldin(bp, bo + c + 1, f);
    }
    if (GNET) {
        if (tid < 128) ex_s[tid] = (tid < DIMN) ? ldin(b_out, tid, f) : 0.f;
    } else {
        if (tid < 256) ex_s[tid] = ldin(wv_out, tid, f);
    }

    // ---- stage layer-0 input: Sh rows are already [t, S, 0,0,0] -> vector copy ----
    {
        const int r = tid >> 3, j = tid & 7;
        const h16* src = Sh + (row0 + r) * 104;
        h16* dst = &Hs[r][0];
#pragma unroll
        for (int c = j; c < 16; c += 8) {
            if (c < 13)
                *(h16x8*)(dst + c * 8) = *(const h16x8*)(src + c * 8);
            else {
                const h16x8 z = {};
                *(h16x8*)(dst + c * 8) = z;
            }
        }
    }
    __syncthreads();   // staging + bias visible to all waves

    f32x4 acc[2][4];   // acc[wt][rt]: rows rt*16+m, cols nb16+wt*16+quad*4+reg

    // ---- layer 0 (K=128, N=256) ----
    init_acc<2>(acc, &bias_s[0][0], w * 32, quad);
    layer_mfma<128, 2>(P0, Hs, w * 2, m, quad, lane, acc);
    writeback<2>(acc, Hs, w * 32, m, quad);

    // ---- hidden layers 1..3 (K=256, N=256) ----
    for (int li = 1; li < 4; li++) {
        init_acc<2>(acc, &bias_s[li][0], w * 32, quad);
        layer_mfma<256, 2>(Ph + (long)(li - 1) * 65536, Hs, w * 2, m, quad, lane, acc);
        writeback<2>(acc, Hs, w * 32, m, quad);
    }

    if (GNET) {
        // ---- output layer (N=100 pad 128, NTW=1), bias folded into init ----
        init_acc<1>(acc, ex_s, w * 16, quad);
        layer_mfma<256, 1>(Pout, Hs, w, m, quad, lane, acc);

        // stoch = sum_col grad*vol  (vol already has sqrt(h))
        float p[4] = {0.f, 0.f, 0.f, 0.f};
        const int cb = w * 16 + quad * 4;
        if (cb < DIMN) {   // cb multiple of 4 -> cb<=96 -> cb+3<=99
#pragma unroll
            for (int rt = 0; rt < 4; rt++) {
                const long r = row0 + rt * 16 + m;
                const float4 vv = *(const float4*)&vol[r * DIMN + cb];
                p[rt] += acc[0][rt][0] * vv.x + acc[0][rt][1] * vv.y
                       + acc[0][rt][2] * vv.z + acc[0][rt][3] * vv.w;
            }
        }
#pragma unroll
        for (int rt = 0; rt < 4; rt++) {
            float v = p[rt];
            v += __shfl_xor(v, 16);
            v += __shfl_xor(v, 32);
            if (quad == 0) Ps[rt * 16 + m][w] = v;
        }
        __syncthreads();
        if (tid < 64) {
            float s = 0.f;
#pragma unroll
            for (int q = 0; q < 8; q++) s += Ps[tid][q];
            outv[row0 + tid] = s;
        }
    } else {
        // v = Hs . w_out + b_out (256 -> 1), 8 threads per row
        const int r = tid & 63, part = tid >> 6;
        float s = 0.f;
#pragma unroll
        for (int c = 0; c < 4; c++) {
            const h16x8 hv = *(const h16x8*)&Hs[r][part * 32 + c * 8];
#pragma unroll
            for (int q = 0; q < 8; q++)
                s += (float)hv[q] * ex_s[part * 32 + c * 8 + q];
        }
        Ps[r][part] = s;
        __syncthreads();
        if (tid < 64) {
            float s2 = 0.f;
#pragma unroll
            for (int q = 0; q < 8; q++) s2 += Ps[tid][q];
            outv[row0 + tid] = s2 + ldin(b_out, 0, f);
        }
    }
}

// ---------------- final: error accumulation + v_f ----------------
__global__ void final_kernel(const float* __restrict__ v_all, const float* __restrict__ stoch,
                             const void* tgp, void* out, const int* __restrict__ dflag)
{
    const int f = *dflag;
    const int b = blockIdx.x * blockDim.x + threadIdx.x;
    if (b >= NPATH) return;
    float err = 0.f;
    for (int i = 0; i < NT - 1; i++) {
        const float h = ldin(tgp, i + 1, f) - ldin(tgp, i, f);
        const float e = v_all[(i + 1) * NPATH + b] - v_all[i * NPATH + b] * (1.f + RRATE * h)
                        - stoch[i * NPATH + b];
        err += e * e;
    }
    const long eoff = (long)NPATH + (long)NPATH * DIMN;
    const float vf = v_all[(long)(NT - 1) * NPATH + b];
    if (f) {
        ((float*)out)[b] = vf;
        ((float*)out)[eoff + b] = err;
    } else {
        ((bf16*)out)[b] = __float2bfloat16(vf);
        ((bf16*)out)[eoff + b] = __float2bfloat16(err);
    }
}

static inline int imin(int a, int b) { return a < b ? a : b; }

extern "C" void kernel_launch(void* const* d_in, const int* in_sizes, int n_in,
                              void* d_out, int out_size, void* d_ws, size_t ws_size,
                              hipStream_t stream) {
    const void* S0    = d_in[0];
    const void* dW    = d_in[1];
    const void* tg    = d_in[2];
    const void* V     = d_in[3];
    const void* Wg_in = d_in[4];
    const void* bg_in = d_in[5];
    const void* Wg_h  = d_in[6];
    const void* bg_h  = d_in[7];
    const void* Wg_out= d_in[8];
    const void* bg_out= d_in[9];
    const void* Wv_in = d_in[10];
    const void* bv_in = d_in[11];
    const void* Wv_h  = d_in[12];
    const void* bv_h  = d_in[13];
    const void* Wv_out= d_in[14];
    const void* bv_out= d_in[15];

    const size_t SZ_SD  = (size_t)NPATH * DIMN * 4;    // 3.28 MB (f32 per timestep)
    const size_t SZ_SH  = (size_t)NPATH * 104 * 2;     // 1.70 MB (fp16 padded S)

    // ---- carve workspace ----
    char* p = (char*)d_ws;
    auto carve = [&](size_t bytes) -> char* {
        char* r = p;
        p += (bytes + 255) & ~(size_t)255;
        return r;
    };
    int*   dflag     = (int*)carve(256);
    float* S_carry   = (float*)carve(SZ_SD);
    float* Vt        = (float*)carve((size_t)DIMN * DIMN * 4);
    float* v_all     = (float*)carve((size_t)NT * NPATH * 4);
    float* stoch_all = (float*)carve((size_t)(NT - 1) * NPATH * 4);
    h16*   Shf       = (h16*)carve(SZ_SH);
    h16*   Pk        = (h16*)carve((size_t)491520 * 2);     // packed fp16 weights (tiled)
    const size_t fixed = (size_t)(p - (char*)d_ws);

    // packed-weight sub-pointers
    h16* Pg0   = Pk;
    h16* Pgh   = Pk + 32768;
    h16* Pgout = Pk + 229376;
    h16* Pv0   = Pk + 262144;
    h16* Pvh   = Pk + 294912;

    // adaptive time-chunk: per-timestep = D/vol (f32) + Sh (fp16)
    const size_t perC = SZ_SD + SZ_SH;                       // 4.98 MB
    size_t avail = (ws_size > fixed + 65536) ? (ws_size - fixed - 65536) : 0;
    int C = (int)(avail / perC);
    if (C < 1) C = 1;
    if (C > NT - 1) C = NT - 1;
    float* D_chunk = (float*)carve((size_t)C * SZ_SD);       // vol written in-place
    h16*   Sh      = (h16*)carve((size_t)C * SZ_SH);

    // ---- prep ----
    probe_kernel<<<dim3(1), dim3(64), 0, stream>>>(tg, dflag);
    init_kernel<<<dim3((NPATH * DIMN + 255) / 256), dim3(256), 0, stream>>>(S0, S_carry, V, Vt, dflag);
    pack_kernel<<<dim3(1920), dim3(256), 0, stream>>>(Wg_in, Wg_h, Wg_out, Wv_in, Wv_h, Pk, dflag);

    // ---- chunk loop over timesteps t in [0, 49) ----
    for (int t0 = 0; t0 < NT - 1; t0 += C) {
        const int Cg = imin(C, NT - 1 - t0);
        const int rows = Cg * NPATH;

        // D = dW[t0..t0+Cg) @ V^T
        gemm_kernel<true><<<dim3(rows / 128, 1), 256, 0, stream>>>(
            dW, (long)t0 * NPATH * DIMN, DIMN, Vt, DIMN, D_chunk, dflag);

        // scan: Sh (fp16), vol in-place over D, advance S_carry; S_f + Shf on last chunk
        scan_chunk_kernel<<<dim3((NPATH * DIMN + 255) / 256), 256, 0, stream>>>(
            S_carry, D_chunk, tg, Sh, t0, Cg, d_out, Shf,
            (t0 + Cg == NT - 1) ? 1 : 0, dflag);

        // g-net (MFMA, fused stoch epilogue)
        mlp16_kernel<true><<<dim3(rows / 64), 512, 0, stream>>>(
            Sh, D_chunk, Pg0, Pgh, Pgout, bg_in, bg_h, bg_out,
            nullptr, tg, t0, stoch_all + (long)t0 * NPATH, dflag);

        // v-net (MFMA, fused output dot)
        mlp16_kernel<false><<<dim3(rows / 64), 512, 0, stream>>>(
            Sh, nullptr, Pv0, Pvh, nullptr, bv_in, bv_h, bv_out,
            Wv_out, tg, t0, v_all + (long)t0 * NPATH, dflag);
    }

    // ---- v at t = 49 from Shf ----
    mlp16_kernel<false><<<dim3(NPATH / 64), 512, 0, stream>>>(
        Shf, nullptr, Pv0, Pvh, nullptr, bv_in, bv_h, bv_out,
        Wv_out, tg, NT - 1, v_all + (long)(NT - 1) * NPATH, dflag);

    // ---- error + v_f ----
    final_kernel<<<dim3(NPATH / 256), 256, 0, stream>>>(v_all, stoch_all, tg, d_out, dflag);
}

// Round 6
// 981.014 us; speedup vs baseline: 1.4069x; 1.1545x over previous
//
#include <hip/hip_runtime.h>
#include <hip/hip_bf16.h>

// Problem constants (match reference)
#define DIMN 100
#define NPATH 8192
#define NT 50
#define HW 256
#define RRATE 0.05f

typedef __hip_bfloat16 bf16;
typedef _Float16 h16;
typedef __attribute__((ext_vector_type(8))) _Float16 h16x8;
typedef __attribute__((ext_vector_type(4))) _Float16 h16x4;
typedef __attribute__((ext_vector_type(4))) float f32x4;

// dtype-flag-branched raw-input loader: f32 != 0 -> fp32 array, else bf16 array
__device__ __forceinline__ float ldin(const void* p, long i, int f32) {
    return f32 ? ((const float*)p)[i] : __bfloat162float(((const bf16*)p)[i]);
}

// ---------------- probe input dtype ----------------
__global__ void probe_kernel(const void* tgp, int* flag) {
    if (threadIdx.x == 0 && blockIdx.x == 0) {
        const unsigned short* u = (const unsigned short*)tgp;
        *flag = (u[1] == 0) ? 1 : 0;   // fp32: high half of 0.0f == 0
    }
}

// ---------------- init: S_carry (f32) from S0 ----------
__global__ void init_kernel(const void* S0, float* S_carry, const int* dflag) {
    const int f = *dflag;
    const long i = (long)blockIdx.x * blockDim.x + threadIdx.x;
    if (i < (long)NPATH * DIMN) S_carry[i] = ldin(S0, i, f);
}

// ---------------- pack all MLP weights, MFMA-TILE-CONTIGUOUS fp16 ----------------
// Each 16(n)x32(k) tile = 512 h16 = 1KB contiguous, laid out in MFMA lane order:
//   tile(tn,tk) element (lane,e) = W^T[tn*16+(lane&15)][tk*32+(lane>>4)*8+e]
// so a wave's fragment load is exactly base + lane*16B (fully coalesced).
// Tile order: row-major (tn, tk). Matrix offsets (h16): Pg0=0 (16x4 tiles),
// Pgh=32768 (3x 16x8), Pgout=229376 (8x8), Pv0=262144 (16x4), Pvh=294912 (3x 16x8),
// VH=491520 (7x4, V hi-fp16), VL=505856 (7x4, V lo-fp16 residual). Total 520192.
__global__ void pack_kernel(const void* Wg_in, const void* Wg_h, const void* Wg_out,
                            const void* Wv_in, const void* Wv_h, const void* Vmat,
                            h16* __restrict__ P, const int* __restrict__ dflag)
{
    const int f = *dflag;
    const long i = (long)blockIdx.x * blockDim.x + threadIdx.x;
    if (i >= 520192) return;
    if (i >= 491520) {   // V hi/lo planes for the dW @ V^T gemm (W^T[d][k] = V[d][k])
        const long j0 = i - 491520;
        const int plane = (j0 >= 14336) ? 1 : 0;
        const long j = plane ? (j0 - 14336) : j0;
        const int tile = (int)(j >> 9), lane = (int)((j >> 3) & 63), e = (int)(j & 7);
        const int tn = tile >> 2, tk = tile & 3;
        const int d = tn * 16 + (lane & 15);
        const int k = tk * 32 + (lane >> 4) * 8 + e;
        float v = (d < DIMN && k < DIMN) ? ldin(Vmat, (long)d * DIMN + k, f) : 0.f;
        const h16 hh = (h16)v;
        P[i] = plane ? (h16)(v - (float)hh) : hh;
        return;
    }
    long j; int NTk, kind; const void* src; long soff = 0;
    if (i < 32768)       { j = i;          NTk = 4; kind = 0; src = Wg_in; }
    else if (i < 229376) { long t = i - 32768;  j = t & 65535; NTk = 8; kind = 1; src = Wg_h;
                           soff = (long)(t >> 16) * 65536; }
    else if (i < 262144) { j = i - 229376; NTk = 8; kind = 2; src = Wg_out; }
    else if (i < 294912) { j = i - 262144; NTk = 4; kind = 0; src = Wv_in; }
    else                 { long t = i - 294912; j = t & 65535; NTk = 8; kind = 1; src = Wv_h;
                           soff = (long)(t >> 16) * 65536; }
    const int tile = (int)(j >> 9), lane = (int)((j >> 3) & 63), e = (int)(j & 7);
    const int tn = tile / NTk, tk = tile - tn * NTk;
    const int n = tn * 16 + (lane & 15);
    const int k = tk * 32 + (lane >> 4) * 8 + e;
    float v;
    if (kind == 0)      v = (k < 101) ? ldin(src, (long)k * 256 + n, f) : 0.f;  // W_in [101][256]
    else if (kind == 1) v = ldin(src, soff + (long)k * 256 + n, f);             // W_h  [256][256]
    else                v = (n < 100) ? ldin(src, (long)k * 100 + n, f) : 0.f;  // W_out[256][100]
    P[i] = (h16)v;
}

// ---------------- split-fp16 MFMA gemm: D = dW @ V^T (f32 out) ----------------
// dW = hi+lo (fp16 split; exact for bf16 inputs since bf16 ⊂ fp16 mantissa),
// V likewise (packed planes VH/VL). D = lo*Vh + hi*Vl + hi*Vh, fp32 MFMA acc
// -> matches the fp32 gemm to ~1e-6 relative or better.
// 64 rows/block, 4 waves x 2 n-tiles (n-tiles 0..6 active of 8; tile 7 clamped
// to 6 and its accumulator discarded). Transposed-output: mfma(w,h,acc) gives
// row = rt*16 + (lane&15), col = tn*16 + quad*4 + reg.
__global__ __launch_bounds__(256, 4)
void gemm16_kernel(const void* dWp, long aOff, const h16* __restrict__ PH,
                   const h16* __restrict__ PL, float* __restrict__ Dout,
                   const int* __restrict__ dflag)
{
    const int f = *dflag;
    __shared__ __align__(16) h16 AH[64][136];   // 17,408 B
    __shared__ __align__(16) h16 AL[64][136];   // 17,408 B
    const int tid = threadIdx.x;
    const int w = tid >> 6, lane = tid & 63, quad = lane >> 4, m = lane & 15;
    const long row0 = (long)blockIdx.x * 64;

    // ---- stage 64x100 dW slab (coalesced) with hi/lo fp16 split ----
    {
        const long base = aOff + row0 * DIMN;
#pragma unroll
        for (int q = 0; q < 25; q++) {
            const int i = tid + 256 * q;        // i < 6400
            const unsigned r = (unsigned)i / 100u;
            const int c = i - (int)r * 100;
            const float x = ldin(dWp, base + i, f);
            const h16 h = (h16)x;
            AH[r][c] = h;
            AL[r][c] = (h16)(x - (float)h);
        }
        const int r = tid >> 2, p = tid & 3;    // zero pad cols 100..127
#pragma unroll
        for (int j = 0; j < 7; j++) {
            AH[r][100 + p * 7 + j] = (h16)0.f;
            AL[r][100 + p * 7 + j] = (h16)0.f;
        }
    }
    __syncthreads();

    f32x4 acc[2][4];
#pragma unroll
    for (int wt = 0; wt < 2; wt++)
#pragma unroll
        for (int rt = 0; rt < 4; rt++) acc[wt][rt] = (f32x4){0.f, 0.f, 0.f, 0.f};

    const int tn0 = w * 2;
    const int tn1c = (tn0 + 1 > 6) ? 6 : tn0 + 1;     // clamp dead tile (no OOB)
    const h16* pwh[2] = { PH + (long)tn0 * 2048 + lane * 8,
                          PH + (long)tn1c * 2048 + lane * 8 };
    const h16* pwl[2] = { PL + (long)tn0 * 2048 + lane * 8,
                          PL + (long)tn1c * 2048 + lane * 8 };
#pragma unroll
    for (int kt = 0; kt < 4; kt++) {
        h16x8 wh[2], wl[2];
#pragma unroll
        for (int wt = 0; wt < 2; wt++) {
            wh[wt] = *(const h16x8*)(pwh[wt] + kt * 512);
            wl[wt] = *(const h16x8*)(pwl[wt] + kt * 512);
        }
#pragma unroll
        for (int rt = 0; rt < 4; rt++) {
            const h16x8 ah = *(const h16x8*)&AH[rt * 16 + m][kt * 32 + quad * 8];
            const h16x8 al = *(const h16x8*)&AL[rt * 16 + m][kt * 32 + quad * 8];
#pragma unroll
            for (int wt = 0; wt < 2; wt++) {
                acc[wt][rt] = __builtin_amdgcn_mfma_f32_16x16x32_f16(wl[wt], ah, acc[wt][rt], 0, 0, 0);
                acc[wt][rt] = __builtin_amdgcn_mfma_f32_16x16x32_f16(wh[wt], al, acc[wt][rt], 0, 0, 0);
                acc[wt][rt] = __builtin_amdgcn_mfma_f32_16x16x32_f16(wh[wt], ah, acc[wt][rt], 0, 0, 0);
            }
        }
    }

    // ---- write D rows (float4, cb multiple of 4, cb<100) ----
#pragma unroll
    for (int wt = 0; wt < 2; wt++) {
        const int cb = (tn0 + wt) * 16 + quad * 4;
        if (cb < DIMN) {
#pragma unroll
            for (int rt = 0; rt < 4; rt++) {
                float4* dp = (float4*)(Dout + (row0 + rt * 16 + m) * (long)DIMN + cb);
                *dp = make_float4(acc[wt][rt][0], acc[wt][rt][1],
                                  acc[wt][rt][2], acc[wt][rt][3]);
            }
        }
    }
}

// ---------------- chunked S scan: emits fp16 S (padded 104), vol in-place over D --
// Sh row layout (104 h16): [0]=t, [1..100]=S, [101..103]=0  (t embedded so the MLP
// staging is a straight vector copy). vol = s*D*sqrt(h); S_new = s*(1+r*h) + vol.
__global__ __launch_bounds__(256)
void scan_chunk_kernel(float* __restrict__ S_carry, float* __restrict__ D,
                       const void* tgp, h16* __restrict__ Sh,
                       int t0, int Cg, void* outBase, h16* __restrict__ Shf,
                       int writeSf, const int* __restrict__ dflag)
{
    const int f = *dflag;
    const long idx = (long)blockIdx.x * blockDim.x + threadIdx.x;
    if (idx >= (long)NPATH * DIMN) return;
    const long b = idx / DIMN;
    const int d = (int)(idx - b * DIMN);
    float s = S_carry[idx];
    for (int lt = 0; lt < Cg; lt++) {
        const int t = t0 + lt;
        const float h = ldin(tgp, t + 1, f) - ldin(tgp, t, f);
        const long off = (long)lt * (NPATH * DIMN) + idx;
        const float vol = s * D[off] * sqrtf(h);
        const long shr = ((long)lt * NPATH + b) * 104;
        Sh[shr + 1 + d] = (h16)s;
        if (d == 0) Sh[shr] = (h16)ldin(tgp, t, f);
        if (d < 3) Sh[shr + 101 + d] = (h16)0.f;
        D[off] = vol;
        s = s + RRATE * s * h + vol;
    }
    S_carry[idx] = s;
    if (writeSf) {
        if (f) ((float*)outBase)[NPATH + idx] = s;
        else   ((bf16*)outBase)[NPATH + idx] = __float2bfloat16(s);
        Shf[b * 104 + 1 + d] = (h16)s;
        if (d == 0) Shf[b * 104] = (h16)ldin(tgp, NT - 1, f);
        if (d < 3) Shf[b * 104 + 101 + d] = (h16)0.f;
    }
}

// ---------------- fused MFMA fp16 MLP building blocks ----------------
// TRANSPOSED-OUTPUT scheme: mfma(w_frag, h_frag, acc) -> D: col(lane&15)=H-row,
// row(quad*4+reg)=output column. Bias folded into acc INIT (MFMA C-in).
// 8 waves/block (512 thr), NTW=2 col-tiles/wave: same LDS per block -> still
// 4 blocks/CU but 32 waves/CU (2x TLP). Weights are tile-contiguous: each wf
// load is base + lane*16B, fully coalesced, constant per-kt offsets.
template<int NTW>
__device__ __forceinline__ void init_acc(f32x4 acc[2][4], const float* __restrict__ bsrc,
                                         int nb16, int quad)
{
#pragma unroll
    for (int wt = 0; wt < NTW; wt++) {
        const f32x4 b4 = *(const f32x4*)(bsrc + nb16 + wt * 16 + quad * 4);
#pragma unroll
        for (int rt = 0; rt < 4; rt++) acc[wt][rt] = b4;
    }
}

template<int KP, int NTW>
__device__ __forceinline__ void layer_mfma(const h16* __restrict__ P,
                                           const h16 (*__restrict__ Hsp)[264],
                                           int tn0, int m, int quad, int lane,
                                           f32x4 acc[2][4])
{
    constexpr int NKT = KP >> 5;            // k-tiles (32 k each)
    constexpr int TSTRIDE = NKT * 512;      // h16 per n-tile row of tiles
    const h16* pw = P + (long)tn0 * TSTRIDE + lane * 8;
    h16x8 wf[2][NTW];
#pragma unroll
    for (int wt = 0; wt < NTW; wt++)
        wf[0][wt] = *(const h16x8*)(pw + wt * TSTRIDE);
#pragma unroll
    for (int wt = 0; wt < NTW; wt++)
        wf[1][wt] = *(const h16x8*)(pw + wt * TSTRIDE + 512);
#pragma unroll
    for (int kt = 0; kt < NKT; kt++) {
#pragma unroll
        for (int rt = 0; rt < 4; rt++) {
            const h16x8 hf = *(const h16x8*)&Hsp[rt * 16 + m][(kt << 5) + quad * 8];
#pragma unroll
            for (int wt = 0; wt < NTW; wt++)
                acc[wt][rt] = __builtin_amdgcn_mfma_f32_16x16x32_f16(
                    wf[kt & 1][wt], hf, acc[wt][rt], 0, 0, 0);
        }
        if (kt + 2 < NKT) {
#pragma unroll
            for (int wt = 0; wt < NTW; wt++)
                wf[kt & 1][wt] = *(const h16x8*)(pw + wt * TSTRIDE + (kt + 2) * 512);
        }
    }
}

template<int NTW>
__device__ __forceinline__ void writeback(f32x4 acc[2][4], h16 (*Hsp)[264],
                                          int nb16, int m, int quad)
{
    __syncthreads();   // all waves done READING Hs this layer
#pragma unroll
    for (int wt = 0; wt < NTW; wt++) {
        const int cb = nb16 + wt * 16 + quad * 4;
#pragma unroll
        for (int rt = 0; rt < 4; rt++) {
            const h16x4 pk = {(h16)fmaxf(acc[wt][rt][0], 0.f),
                              (h16)fmaxf(acc[wt][rt][1], 0.f),
                              (h16)fmaxf(acc[wt][rt][2], 0.f),
                              (h16)fmaxf(acc[wt][rt][3], 0.f)};
            *(h16x4*)&Hsp[rt * 16 + m][cb] = pk;
        }
    }
    __syncthreads();   // writes visible before next layer reads
}

// ---------------- fused MFMA fp16 MLP: 64 rows/block, 8 waves split N ----------
template <bool GNET>
__global__ __launch_bounds__(512, 8)
void mlp16_kernel(const h16* __restrict__ Sh, const float* __restrict__ vol,
                  const h16* __restrict__ P0, const h16* __restrict__ Ph,
                  const h16* __restrict__ Pout,
                  const void* b_in, const void* b_h, const void* b_out,
                  const void* wv_out, const void* tgp, int t0,
                  float* __restrict__ outv, const int* __restrict__ dflag)
{
    const int f = *dflag;
    __shared__ __align__(16) h16 Hs[64][264];       // 33,792 B
    __shared__ __align__(16) float bias_s[4][256];  // 4,096 B
    __shared__ __align__(16) float ex_s[256];       // 1,024 B (GNET: b_out pad; VNET: wv_out)
    __shared__ float Ps[64][8];                     // 2,048 B  (total 40,960 = 4 blocks/CU)
    const int tid = threadIdx.x;
    const int w = tid >> 6, lane = tid & 63, quad = lane >> 4, m = lane & 15;
    const long row0 = (long)blockIdx.x * 64;

    // ---- preload biases (+ extra vector) into LDS (512 threads, 2 each) ----
    {
        const int l = tid >> 7, c = (tid & 127) << 1;
        const void* bp = (l == 0) ? b_in : b_h;
        const long bo = (l == 0) ? 0 : (long)(l - 1) * 256;
        bias_s[l][c]     = ldin(bp, bo + c, f);
        bias_s[l][c + 1] = ldin(bp, bo + c + 1, f);
    }
    if (GNET) {
        if (tid < 128) ex_s[tid] = (tid < DIMN) ? ldin(b_out, tid, f) : 0.f;
    } else {
        if (tid < 256) ex_s[tid] = ldin(wv_out, tid, f);
    }

    // ---- stage layer-0 input: Sh rows are already [t, S, 0,0,0] -> vector copy ----
    {
        const int r = tid >> 3, j = tid & 7;
        const h16* src = Sh + (row0 + r) * 104;
        h16* dst = &Hs[r][0];
#pragma unroll
        for (int c = j; c < 16; c += 8) {
            if (c < 13)
                *(h16x8*)(dst + c * 8) = *(const h16x8*)(src + c * 8);
            else {
                const h16x8 z = {};
                *(h16x8*)(dst + c * 8) = z;
            }
        }
    }
    __syncthreads();   // staging + bias visible to all waves

    f32x4 acc[2][4];   // acc[wt][rt]: rows rt*16+m, cols nb16+wt*16+quad*4+reg

    // ---- layer 0 (K=128, N=256) ----
    init_acc<2>(acc, &bias_s[0][0], w * 32, quad);
    layer_mfma<128, 2>(P0, Hs, w * 2, m, quad, lane, acc);
    writeback<2>(acc, Hs, w * 32, m, quad);

    // ---- hidden layers 1..3 (K=256, N=256) ----
    for (int li = 1; li < 4; li++) {
        init_acc<2>(acc, &bias_s[li][0], w * 32, quad);
        layer_mfma<256, 2>(Ph + (long)(li - 1) * 65536, Hs, w * 2, m, quad, lane, acc);
        writeback<2>(acc, Hs, w * 32, m, quad);
    }

    if (GNET) {
        // ---- output layer (N=100 pad 128, NTW=1), bias folded into init ----
        init_acc<1>(acc, ex_s, w * 16, quad);
        layer_mfma<256, 1>(Pout, Hs, w, m, quad, lane, acc);

        // stoch = sum_col grad*vol  (vol already has sqrt(h))
        float p[4] = {0.f, 0.f, 0.f, 0.f};
        const int cb = w * 16 + quad * 4;
        if (cb < DIMN) {   // cb multiple of 4 -> cb<=96 -> cb+3<=99
#pragma unroll
            for (int rt = 0; rt < 4; rt++) {
                const long r = row0 + rt * 16 + m;
                const float4 vv = *(const float4*)&vol[r * DIMN + cb];
                p[rt] += acc[0][rt][0] * vv.x + acc[0][rt][1] * vv.y
                       + acc[0][rt][2] * vv.z + acc[0][rt][3] * vv.w;
            }
        }
#pragma unroll
        for (int rt = 0; rt < 4; rt++) {
            float v = p[rt];
            v += __shfl_xor(v, 16);
            v += __shfl_xor(v, 32);
            if (quad == 0) Ps[rt * 16 + m][w] = v;
        }
        __syncthreads();
        if (tid < 64) {
            float s = 0.f;
#pragma unroll
            for (int q = 0; q < 8; q++) s += Ps[tid][q];
            outv[row0 + tid] = s;
        }
    } else {
        // v = Hs . w_out + b_out (256 -> 1), 8 threads per row
        const int r = tid & 63, part = tid >> 6;
        float s = 0.f;
#pragma unroll
        for (int c = 0; c < 4; c++) {
            const h16x8 hv = *(const h16x8*)&Hs[r][part * 32 + c * 8];
#pragma unroll
            for (int q = 0; q < 8; q++)
                s += (float)hv[q] * ex_s[part * 32 + c * 8 + q];
        }
        Ps[r][part] = s;
        __syncthreads();
        if (tid < 64) {
            float s2 = 0.f;
#pragma unroll
            for (int q = 0; q < 8; q++) s2 += Ps[tid][q];
            outv[row0 + tid] = s2 + ldin(b_out, 0, f);
        }
    }
}

// ---------------- final: error accumulation + v_f ----------------
__global__ void final_kernel(const float* __restrict__ v_all, const float* __restrict__ stoch,
                             const void* tgp, void* out, const int* __restrict__ dflag)
{
    const int f = *dflag;
    const int b = blockIdx.x * blockDim.x + threadIdx.x;
    if (b >= NPATH) return;
    float err = 0.f;
    for (int i = 0; i < NT - 1; i++) {
        const float h = ldin(tgp, i + 1, f) - ldin(tgp, i, f);
        const float e = v_all[(i + 1) * NPATH + b] - v_all[i * NPATH + b] * (1.f + RRATE * h)
                        - stoch[i * NPATH + b];
        err += e * e;
    }
    const long eoff = (long)NPATH + (long)NPATH * DIMN;
    const float vf = v_all[(long)(NT - 1) * NPATH + b];
    if (f) {
        ((float*)out)[b] = vf;
        ((float*)out)[eoff + b] = err;
    } else {
        ((bf16*)out)[b] = __float2bfloat16(vf);
        ((bf16*)out)[eoff + b] = __float2bfloat16(err);
    }
}

static inline int imin(int a, int b) { return a < b ? a : b; }

extern "C" void kernel_launch(void* const* d_in, const int* in_sizes, int n_in,
                              void* d_out, int out_size, void* d_ws, size_t ws_size,
                              hipStream_t stream) {
    const void* S0    = d_in[0];
    const void* dW    = d_in[1];
    const void* tg    = d_in[2];
    const void* V     = d_in[3];
    const void* Wg_in = d_in[4];
    const void* bg_in = d_in[5];
    const void* Wg_h  = d_in[6];
    const void* bg_h  = d_in[7];
    const void* Wg_out= d_in[8];
    const void* bg_out= d_in[9];
    const void* Wv_in = d_in[10];
    const void* bv_in = d_in[11];
    const void* Wv_h  = d_in[12];
    const void* bv_h  = d_in[13];
    const void* Wv_out= d_in[14];
    const void* bv_out= d_in[15];

    const size_t SZ_SD  = (size_t)NPATH * DIMN * 4;    // 3.28 MB (f32 per timestep)
    const size_t SZ_SH  = (size_t)NPATH * 104 * 2;     // 1.70 MB (fp16 padded S)

    // ---- carve workspace ----
    char* p = (char*)d_ws;
    auto carve = [&](size_t bytes) -> char* {
        char* r = p;
        p += (bytes + 255) & ~(size_t)255;
        return r;
    };
    int*   dflag     = (int*)carve(256);
    float* S_carry   = (float*)carve(SZ_SD);
    float* v_all     = (float*)carve((size_t)NT * NPATH * 4);
    float* stoch_all = (float*)carve((size_t)(NT - 1) * NPATH * 4);
    h16*   Shf       = (h16*)carve(SZ_SH);
    h16*   Pk        = (h16*)carve((size_t)520192 * 2);     // packed fp16 weights (tiled)
    const size_t fixed = (size_t)(p - (char*)d_ws);

    // packed-weight sub-pointers
    h16* Pg0   = Pk;
    h16* Pgh   = Pk + 32768;
    h16* Pgout = Pk + 229376;
    h16* Pv0   = Pk + 262144;
    h16* Pvh   = Pk + 294912;
    h16* PvtH  = Pk + 491520;
    h16* PvtL  = Pk + 505856;

    // adaptive time-chunk: per-timestep = D/vol (f32) + Sh (fp16)
    const size_t perC = SZ_SD + SZ_SH;                       // 4.98 MB
    size_t avail = (ws_size > fixed + 65536) ? (ws_size - fixed - 65536) : 0;
    int C = (int)(avail / perC);
    if (C < 1) C = 1;
    if (C > NT - 1) C = NT - 1;
    float* D_chunk = (float*)carve((size_t)C * SZ_SD);       // vol written in-place
    h16*   Sh      = (h16*)carve((size_t)C * SZ_SH);

    // ---- prep ----
    probe_kernel<<<dim3(1), dim3(64), 0, stream>>>(tg, dflag);
    init_kernel<<<dim3((NPATH * DIMN + 255) / 256), dim3(256), 0, stream>>>(S0, S_carry, dflag);
    pack_kernel<<<dim3(2032), dim3(256), 0, stream>>>(Wg_in, Wg_h, Wg_out, Wv_in, Wv_h, V, Pk, dflag);

    // ---- chunk loop over timesteps t in [0, 49) ----
    for (int t0 = 0; t0 < NT - 1; t0 += C) {
        const int Cg = imin(C, NT - 1 - t0);
        const int rows = Cg * NPATH;

        // D = dW[t0..t0+Cg) @ V^T  (split-fp16 MFMA, f32-equivalent)
        gemm16_kernel<<<dim3(rows / 64), 256, 0, stream>>>(
            dW, (long)t0 * NPATH * DIMN, PvtH, PvtL, D_chunk, dflag);

        // scan: Sh (fp16), vol in-place over D, advance S_carry; S_f + Shf on last chunk
        scan_chunk_kernel<<<dim3((NPATH * DIMN + 255) / 256), 256, 0, stream>>>(
            S_carry, D_chunk, tg, Sh, t0, Cg, d_out, Shf,
            (t0 + Cg == NT - 1) ? 1 : 0, dflag);

        // g-net (MFMA, fused stoch epilogue)
        mlp16_kernel<true><<<dim3(rows / 64), 512, 0, stream>>>(
            Sh, D_chunk, Pg0, Pgh, Pgout, bg_in, bg_h, bg_out,
            nullptr, tg, t0, stoch_all + (long)t0 * NPATH, dflag);

        // v-net (MFMA, fused output dot)
        mlp16_kernel<false><<<dim3(rows / 64), 512, 0, stream>>>(
            Sh, nullptr, Pv0, Pvh, nullptr, bv_in, bv_h, bv_out,
            Wv_out, tg, t0, v_all + (long)t0 * NPATH, dflag);
    }

    // ---- v at t = 49 from Shf ----
    mlp16_kernel<false><<<dim3(NPATH / 64), 512, 0, stream>>>(
        Shf, nullptr, Pv0, Pvh, nullptr, bv_in, bv_h, bv_out,
        Wv_out, tg, NT - 1, v_all + (long)(NT - 1) * NPATH, dflag);

    // ---- error + v_f ----
    final_kernel<<<dim3(NPATH / 256), 256, 0, stream>>>(v_all, stoch_all, tg, d_out, dflag);
}